// Round 2
// baseline (933.010 us; speedup 1.0000x reference)
//
#include <hip/hip_runtime.h>

#define NWIN 2048
#define NPOS 64
#define DIM  192
#define C3   576
#define HEADS 6
#define HD   32
#define MTOT (NWIN*NPOS)
#define SCALE 0.17677669529663687f

typedef __bf16 b16x8 __attribute__((ext_vector_type(8)));
typedef float  f32x4 __attribute__((ext_vector_type(4)));

// load 8 contiguous elements as bf16x8, converting if fp32
__device__ __forceinline__ b16x8 ld8(const float* p) {
    const f32x4 f0 = *(const f32x4*)p;
    const f32x4 f1 = *(const f32x4*)(p + 4);
    b16x8 r;
    r[0] = (__bf16)f0[0]; r[1] = (__bf16)f0[1]; r[2] = (__bf16)f0[2]; r[3] = (__bf16)f0[3];
    r[4] = (__bf16)f1[0]; r[5] = (__bf16)f1[1]; r[6] = (__bf16)f1[2]; r[7] = (__bf16)f1[3];
    return r;
}
__device__ __forceinline__ b16x8 ld8(const __bf16* p) { return *(const b16x8*)p; }

// ---------------------------------------------------------------------------
// GEMM (B^T form): C[m][n] = sum_k A[m][k] * W[n][k] + bias[n]
// A: M x 192 row-major (TA = float or bf16), W: N x 192 row-major fp32.
// Tile 128(M) x 64(N), BK=64 (3 chunks), 256 threads = 4 waves.
// LDS staged as bf16 (fp32->bf16 convert during staging), fp32 accumulate.
// ---------------------------------------------------------------------------
#define GTM 128
#define GTN 64
#define GLD 72

template <typename TA, typename TC>
__global__ __launch_bounds__(256, 2)
void gemm_bt(const TA* __restrict__ A, const float* __restrict__ W,
             const float* __restrict__ bias, TC* __restrict__ C, int N)
{
    __shared__ __bf16 As[GTM][GLD];
    __shared__ __bf16 Ws[GTN][GLD];
    const int ntiles = N / GTN;
    const int bm = blockIdx.x / ntiles;
    const int bn = blockIdx.x % ntiles;
    const long m0 = (long)bm * GTM;
    const int  n0 = bn * GTN;
    const int tid  = threadIdx.x;
    const int wave = tid >> 6, lane = tid & 63;
    const int lr = lane & 15, lq = lane >> 4;

    f32x4 acc[2][4];
#pragma unroll
    for (int i = 0; i < 2; i++)
#pragma unroll
        for (int j = 0; j < 4; j++) acc[i][j] = (f32x4){0.f, 0.f, 0.f, 0.f};

    for (int kc = 0; kc < 3; kc++) {
        // stage A tile: 128 rows x 64 cols, 8 elems per thread-iter
#pragma unroll
        for (int i = 0; i < 4; i++) {
            int idx = tid + i * 256;
            int r = idx >> 3, c = idx & 7;
            *(b16x8*)&As[r][c * 8] = ld8(A + (m0 + r) * 192 + kc * 64 + c * 8);
        }
        // stage W tile: 64 rows x 64 cols
#pragma unroll
        for (int i = 0; i < 2; i++) {
            int idx = tid + i * 256;
            int r = idx >> 3, c = idx & 7;
            *(b16x8*)&Ws[r][c * 8] = ld8(W + (long)(n0 + r) * 192 + kc * 64 + c * 8);
        }
        __syncthreads();
#pragma unroll
        for (int kt = 0; kt < 2; kt++) {
            const int k0 = kt * 32 + lq * 8;
            b16x8 a0 = *(const b16x8*)&As[wave * 32 + lr][k0];
            b16x8 a1 = *(const b16x8*)&As[wave * 32 + 16 + lr][k0];
            b16x8 b0 = *(const b16x8*)&Ws[lr][k0];
            b16x8 b1 = *(const b16x8*)&Ws[16 + lr][k0];
            b16x8 b2 = *(const b16x8*)&Ws[32 + lr][k0];
            b16x8 b3 = *(const b16x8*)&Ws[48 + lr][k0];
            acc[0][0] = __builtin_amdgcn_mfma_f32_16x16x32_bf16(a0, b0, acc[0][0], 0, 0, 0);
            acc[0][1] = __builtin_amdgcn_mfma_f32_16x16x32_bf16(a0, b1, acc[0][1], 0, 0, 0);
            acc[0][2] = __builtin_amdgcn_mfma_f32_16x16x32_bf16(a0, b2, acc[0][2], 0, 0, 0);
            acc[0][3] = __builtin_amdgcn_mfma_f32_16x16x32_bf16(a0, b3, acc[0][3], 0, 0, 0);
            acc[1][0] = __builtin_amdgcn_mfma_f32_16x16x32_bf16(a1, b0, acc[1][0], 0, 0, 0);
            acc[1][1] = __builtin_amdgcn_mfma_f32_16x16x32_bf16(a1, b1, acc[1][1], 0, 0, 0);
            acc[1][2] = __builtin_amdgcn_mfma_f32_16x16x32_bf16(a1, b2, acc[1][2], 0, 0, 0);
            acc[1][3] = __builtin_amdgcn_mfma_f32_16x16x32_bf16(a1, b3, acc[1][3], 0, 0, 0);
        }
        __syncthreads();
    }
    // epilogue: C/D layout col = lane&15, row = (lane>>4)*4 + reg  (m89-verified)
#pragma unroll
    for (int tn = 0; tn < 4; tn++) {
        float bv = bias[n0 + tn * 16 + lr];
#pragma unroll
        for (int tm = 0; tm < 2; tm++) {
#pragma unroll
            for (int r = 0; r < 4; r++) {
                long row = m0 + wave * 32 + tm * 16 + lq * 4 + r;
                C[row * N + (n0 + tn * 16 + lr)] = (TC)(acc[tm][tn][r] + bv);
            }
        }
    }
}

// ---------------------------------------------------------------------------
// Fused depthwise-conv + window attention. One block per window b (384 thr =
// 6 waves = 6 heads). The 3x3 depthwise conv runs over the (B_, N) grid, so
// window b needs t rows b-1, b, b+1 (zero-padded at ends).
//  Phase A: conv for k,v channels (o in [192,576)) -> LDS, coalesced.
//  Phase B: conv for this lane's q row (pos = lane, head = wave) -> registers.
//  Phase C: per-lane streaming attention row: s = q.k + rpb + mask, e=exp(s)
//           (logits bounded |s|<~1, max-subtraction skipped - identical
//           softmax), o += e*v, final o/sum -> ctx.
// LDS: 12 (head,k/v) x 64 pos x 40 (=32+8 pad) bf16 = 61440 B.
// ---------------------------------------------------------------------------
__global__ __launch_bounds__(384, 2)
void attn_fused(const __bf16* __restrict__ t, const float* __restrict__ dw_w,
                const float* __restrict__ dw_b, const float* __restrict__ mask,
                const float* __restrict__ rpb, const int* __restrict__ rel_idx,
                __bf16* __restrict__ ctx)
{
    __shared__ __bf16 kvs[12 * 64 * 40];
    const int b = blockIdx.x;
    const int tid = threadIdx.x;
    const int wave = tid >> 6, lane = tid & 63;
    const int h = wave;  // 6 waves exactly

    // ---- Phase A: k,v conv into LDS ----
    {
        const int pr = tid % 192;       // channel pair within k|v block
        const int nb = tid / 192;       // 0 or 1 (even/odd positions)
        const int o  = 192 + pr * 2;    // global channel (even)
        const int cc = pr * 2;
        const int wh = cc / 192;        // 0 = k, 1 = v
        const int rr = cc % 192;
        const int hh = rr / 32, d = rr % 32;
        float wk0[9], wk1[9];
#pragma unroll
        for (int tap = 0; tap < 9; tap++) {
            wk0[tap] = dw_w[o * 9 + tap];
            wk1[tap] = dw_w[(o + 1) * 9 + tap];
        }
        const float bias0 = dw_b[o], bias1 = dw_b[o + 1];
        __bf16* dst0 = &kvs[((hh * 2 + wh) * 64) * 40 + d];
        for (int it = 0; it < 32; it++) {
            const int n = nb + it * 2;
            float a0 = bias0, a1 = bias1;
#pragma unroll
            for (int kh = 0; kh < 3; kh++) {
                const int bb = b + kh - 1;
                if (bb < 0 || bb >= NWIN) continue;  // block-uniform branch
#pragma unroll
                for (int kw = 0; kw < 3; kw++) {
                    const int nn = n + kw - 1;
                    if (nn < 0 || nn >= NPOS) continue;
                    const __bf16* pp = t + (long)(bb * NPOS + nn) * C3 + o;
                    a0 += (float)pp[0] * wk0[kh * 3 + kw];
                    a1 += (float)pp[1] * wk1[kh * 3 + kw];
                }
            }
            dst0[n * 40]     = (__bf16)a0;
            dst0[n * 40 + 1] = (__bf16)a1;
        }
    }

    // ---- Phase B: q row for (pos = lane, head = h) in registers ----
    float q[HD];
#pragma unroll
    for (int d = 0; d < HD; d++) q[d] = dw_b[h * HD + d];
#pragma unroll
    for (int kh = 0; kh < 3; kh++) {
        const int bb = b + kh - 1;
        if (bb < 0 || bb >= NWIN) continue;
#pragma unroll
        for (int kw = 0; kw < 3; kw++) {
            const int nn = lane + kw - 1;
            if (nn >= 0 && nn < NPOS) {
                const b16x8* p = (const b16x8*)(t + (long)(bb * NPOS + nn) * C3 + h * HD);
#pragma unroll
                for (int j = 0; j < 4; j++) {
                    b16x8 vv = p[j];
#pragma unroll
                    for (int e = 0; e < 8; e++)
                        q[j * 8 + e] += (float)vv[e] * dw_w[(h * HD + j * 8 + e) * 9 + kh * 3 + kw];
                }
            }
        }
    }
#pragma unroll
    for (int d = 0; d < HD; d++) q[d] *= SCALE;

    __syncthreads();

    // ---- Phase C: streaming attention (lane = score row) ----
    const __bf16* kbase = &kvs[(h * 2 + 0) * 64 * 40];
    const __bf16* vbase = &kvs[(h * 2 + 1) * 64 * 40];
    const int*    ri    = rel_idx + lane * 64;
    const float*  mrow  = mask + ((long)(b & 63) * 64 + lane) * 64;
    float o_acc[HD];
#pragma unroll
    for (int d = 0; d < HD; d++) o_acc[d] = 0.f;
    float sum = 0.f;
    for (int n = 0; n < 64; n++) {
        const b16x8* kr = (const b16x8*)(kbase + n * 40);   // broadcast read
        float s = 0.f;
#pragma unroll
        for (int j = 0; j < 4; j++) {
            b16x8 kv = kr[j];
#pragma unroll
            for (int e = 0; e < 8; e++) s += q[j * 8 + e] * (float)kv[e];
        }
        s += rpb[ri[n] * HEADS + h] + mrow[n];
        float ee = __expf(s);
        sum += ee;
        const b16x8* vr = (const b16x8*)(vbase + n * 40);   // broadcast read
#pragma unroll
        for (int j = 0; j < 4; j++) {
            b16x8 vv = vr[j];
#pragma unroll
            for (int e = 0; e < 8; e++) o_acc[j * 8 + e] += ee * (float)vv[e];
        }
    }
    const float inv = 1.f / sum;
    __bf16* dst = ctx + (long)(b * NPOS + lane) * DIM + h * HD;
#pragma unroll
    for (int j = 0; j < 4; j++) {
        b16x8 pk;
#pragma unroll
        for (int e = 0; e < 8; e++) pk[e] = (__bf16)(o_acc[j * 8 + e] * inv);
        *(b16x8*)(dst + j * 8) = pk;
    }
}

// ---------------------------------------------------------------------------
extern "C" void kernel_launch(void* const* d_in, const int* in_sizes, int n_in,
                              void* d_out, int out_size, void* d_ws, size_t ws_size,
                              hipStream_t stream)
{
    (void)in_sizes; (void)n_in; (void)out_size; (void)ws_size;
    const float* x      = (const float*)d_in[0];
    const float* mask   = (const float*)d_in[1];
    const float* qkv_w  = (const float*)d_in[2];
    const float* qkv_b  = (const float*)d_in[3];
    const float* dw_w   = (const float*)d_in[4];
    const float* dw_b   = (const float*)d_in[5];
    const float* rpb    = (const float*)d_in[6];
    const int*   rel_i  = (const int*)d_in[7];
    const float* proj_w = (const float*)d_in[8];
    const float* proj_b = (const float*)d_in[9];
    float* out = (float*)d_out;

    __bf16* t   = (__bf16*)d_ws;                 // (131072, 576) bf16 = 151 MB
    __bf16* ctx = t + (long)MTOT * C3;           // (131072, 192) bf16 =  50 MB

    gemm_bt<float, __bf16><<<(MTOT / GTM) * (C3 / GTN), 256, 0, stream>>>(x, qkv_w, qkv_b, t, C3);
    attn_fused<<<NWIN, 384, 0, stream>>>(t, dw_w, dw_b, mask, rpb, rel_i, ctx);
    gemm_bt<__bf16, float><<<(MTOT / GTM) * (DIM / GTN), 256, 0, stream>>>(ctx, proj_w, proj_b, out, DIM);
}

// Round 3
// 710.657 us; speedup vs baseline: 1.3129x; 1.3129x over previous
//
#include <hip/hip_runtime.h>

#define NWIN 2048
#define NPOS 64
#define DIM  192
#define C3   576
#define HEADS 6
#define HD   32
#define MTOT (NWIN*NPOS)
#define SCALE 0.17677669529663687f

typedef __bf16 b16x8 __attribute__((ext_vector_type(8)));
typedef float  f32x4 __attribute__((ext_vector_type(4)));

// load 8 contiguous elements as bf16x8, converting if fp32
__device__ __forceinline__ b16x8 ld8(const float* p) {
    const f32x4 f0 = *(const f32x4*)p;
    const f32x4 f1 = *(const f32x4*)(p + 4);
    b16x8 r;
    r[0] = (__bf16)f0[0]; r[1] = (__bf16)f0[1]; r[2] = (__bf16)f0[2]; r[3] = (__bf16)f0[3];
    r[4] = (__bf16)f1[0]; r[5] = (__bf16)f1[1]; r[6] = (__bf16)f1[2]; r[7] = (__bf16)f1[3];
    return r;
}
__device__ __forceinline__ b16x8 ld8(const __bf16* p) { return *(const b16x8*)p; }

// ---------------------------------------------------------------------------
// GEMM (B^T form): C[m][n] = sum_k A[m][k] * W[n][k] + bias[n]
// Tile 128(M) x 64(N), BK=64 (3 chunks), 256 threads = 4 waves. (unchanged)
// ---------------------------------------------------------------------------
#define GTM 128
#define GTN 64
#define GLD 72

template <typename TA, typename TC>
__global__ __launch_bounds__(256, 2)
void gemm_bt(const TA* __restrict__ A, const float* __restrict__ W,
             const float* __restrict__ bias, TC* __restrict__ C, int N)
{
    __shared__ __bf16 As[GTM][GLD];
    __shared__ __bf16 Ws[GTN][GLD];
    const int ntiles = N / GTN;
    const int bm = blockIdx.x / ntiles;
    const int bn = blockIdx.x % ntiles;
    const long m0 = (long)bm * GTM;
    const int  n0 = bn * GTN;
    const int tid  = threadIdx.x;
    const int wave = tid >> 6, lane = tid & 63;
    const int lr = lane & 15, lq = lane >> 4;

    f32x4 acc[2][4];
#pragma unroll
    for (int i = 0; i < 2; i++)
#pragma unroll
        for (int j = 0; j < 4; j++) acc[i][j] = (f32x4){0.f, 0.f, 0.f, 0.f};

    for (int kc = 0; kc < 3; kc++) {
#pragma unroll
        for (int i = 0; i < 4; i++) {
            int idx = tid + i * 256;
            int r = idx >> 3, c = idx & 7;
            *(b16x8*)&As[r][c * 8] = ld8(A + (m0 + r) * 192 + kc * 64 + c * 8);
        }
#pragma unroll
        for (int i = 0; i < 2; i++) {
            int idx = tid + i * 256;
            int r = idx >> 3, c = idx & 7;
            *(b16x8*)&Ws[r][c * 8] = ld8(W + (long)(n0 + r) * 192 + kc * 64 + c * 8);
        }
        __syncthreads();
#pragma unroll
        for (int kt = 0; kt < 2; kt++) {
            const int k0 = kt * 32 + lq * 8;
            b16x8 a0 = *(const b16x8*)&As[wave * 32 + lr][k0];
            b16x8 a1 = *(const b16x8*)&As[wave * 32 + 16 + lr][k0];
            b16x8 b0 = *(const b16x8*)&Ws[lr][k0];
            b16x8 b1 = *(const b16x8*)&Ws[16 + lr][k0];
            b16x8 b2 = *(const b16x8*)&Ws[32 + lr][k0];
            b16x8 b3 = *(const b16x8*)&Ws[48 + lr][k0];
            acc[0][0] = __builtin_amdgcn_mfma_f32_16x16x32_bf16(a0, b0, acc[0][0], 0, 0, 0);
            acc[0][1] = __builtin_amdgcn_mfma_f32_16x16x32_bf16(a0, b1, acc[0][1], 0, 0, 0);
            acc[0][2] = __builtin_amdgcn_mfma_f32_16x16x32_bf16(a0, b2, acc[0][2], 0, 0, 0);
            acc[0][3] = __builtin_amdgcn_mfma_f32_16x16x32_bf16(a0, b3, acc[0][3], 0, 0, 0);
            acc[1][0] = __builtin_amdgcn_mfma_f32_16x16x32_bf16(a1, b0, acc[1][0], 0, 0, 0);
            acc[1][1] = __builtin_amdgcn_mfma_f32_16x16x32_bf16(a1, b1, acc[1][1], 0, 0, 0);
            acc[1][2] = __builtin_amdgcn_mfma_f32_16x16x32_bf16(a1, b2, acc[1][2], 0, 0, 0);
            acc[1][3] = __builtin_amdgcn_mfma_f32_16x16x32_bf16(a1, b3, acc[1][3], 0, 0, 0);
        }
        __syncthreads();
    }
#pragma unroll
    for (int tn = 0; tn < 4; tn++) {
        float bv = bias[n0 + tn * 16 + lr];
#pragma unroll
        for (int tm = 0; tm < 2; tm++) {
#pragma unroll
            for (int r = 0; r < 4; r++) {
                long row = m0 + wave * 32 + tm * 16 + lq * 4 + r;
                C[row * N + (n0 + tn * 16 + lr)] = (TC)(acc[tm][tn][r] + bv);
            }
        }
    }
}

// ---------------------------------------------------------------------------
// Fused depthwise-conv + window attention, ONE WAVE per (window b, head h).
// grid = NWIN*HEADS blocks x 64 threads. LDS ~9.2 KB -> ~16 blocks/CU
// (vs 61 KB / 2 blocks before); __launch_bounds__(64,4) caps VGPR at 128.
//  Phase A: lane = one of 64 k/v channels of head h; sliding-window 3x3 conv
//           over (window, pos) grid, 3 rolling register rows -> 3 loads/step.
//           Writes kvs[n][c] (64x64 bf16): contiguous 128 B per row.
//  Phase B: lane = query position; conv h's 32 q channels into registers.
//  Phase C: lane = score row; s = q.k + rpb[LDS, closed-form rel idx] + mask,
//           e = expf(s) (logits bounded, max-subtract skipped), o += e*v.
// ---------------------------------------------------------------------------
__global__ __launch_bounds__(64, 4)
void attn_fused(const __bf16* __restrict__ t, const float* __restrict__ dw_w,
                const float* __restrict__ dw_b, const float* __restrict__ mask,
                const float* __restrict__ rpb, __bf16* __restrict__ ctx)
{
    __shared__ __bf16 kvs[64 * 64];   // [n][c]: c<32 = k(d=c), c>=32 = v(d=c-32)
    __shared__ float  rpb_h[225];
    const int bid  = blockIdx.x;
    const int b    = bid / HEADS;
    const int h    = bid % HEADS;
    const int lane = threadIdx.x;

    for (int i = lane; i < 225; i += 64) rpb_h[i] = rpb[i * HEADS + h];

    // ---- Phase A: k,v conv (one channel per lane) ----
    {
        const int kv = lane >> 5, d = lane & 31;
        const int o  = 192 + kv * 192 + h * 32 + d;
        float w[9];
#pragma unroll
        for (int tap = 0; tap < 9; tap++) w[tap] = dw_w[o * 9 + tap];
        const float bias = dw_b[o];
        const bool up = (b > 0), dn = (b < NWIN - 1);
        const __bf16* r1 = t + (long)b * NPOS * C3 + o;
        const __bf16* r0 = r1 - (long)NPOS * C3;
        const __bf16* r2 = r1 + (long)NPOS * C3;
        float p0 = 0.f, c0 = up ? (float)r0[0] : 0.f;
        float p1 = 0.f, c1 = (float)r1[0];
        float p2 = 0.f, c2 = dn ? (float)r2[0] : 0.f;
        for (int nn = 0; nn < 64; nn++) {
            float n0 = 0.f, n1 = 0.f, n2 = 0.f;
            if (nn + 1 < 64) {
                const long off = (long)(nn + 1) * C3;
                if (up) n0 = (float)r0[off];
                n1 = (float)r1[off];
                if (dn) n2 = (float)r2[off];
            }
            float out = bias
                + w[0] * p0 + w[1] * c0 + w[2] * n0
                + w[3] * p1 + w[4] * c1 + w[5] * n1
                + w[6] * p2 + w[7] * c2 + w[8] * n2;
            kvs[nn * 64 + lane] = (__bf16)out;
            p0 = c0; c0 = n0; p1 = c1; c1 = n1; p2 = c2; c2 = n2;
        }
    }

    // ---- Phase B: q row (pos = lane) in registers ----
    float q[HD];
#pragma unroll
    for (int d = 0; d < HD; d++) q[d] = dw_b[h * HD + d];
#pragma unroll
    for (int kh = 0; kh < 3; kh++) {
        const int bb = b + kh - 1;
        if (bb < 0 || bb >= NWIN) continue;   // block-uniform
#pragma unroll
        for (int kw = 0; kw < 3; kw++) {
            const int nn = lane + kw - 1;
            if (nn >= 0 && nn < NPOS) {
                const b16x8* p = (const b16x8*)(t + (long)(bb * NPOS + nn) * C3 + h * HD);
#pragma unroll
                for (int j = 0; j < 4; j++) {
                    b16x8 vv = p[j];
#pragma unroll
                    for (int e = 0; e < 8; e++)
                        q[j * 8 + e] += (float)vv[e] * dw_w[(h * HD + j * 8 + e) * 9 + kh * 3 + kw];
                }
            }
        }
    }
#pragma unroll
    for (int d = 0; d < HD; d++) q[d] *= SCALE;

    __syncthreads();

    // ---- Phase C: streaming attention row (lane = query pos) ----
    const float* mrow = mask + ((long)(b & 63) * 64 + lane) * 64;
    const int hi = lane >> 3, wi = lane & 7;
    float o_acc[HD];
#pragma unroll
    for (int d = 0; d < HD; d++) o_acc[d] = 0.f;
    float sum = 0.f;
    for (int n = 0; n < 64; n++) {
        const b16x8* kr = (const b16x8*)(kvs + n * 64);        // broadcast
        float s = 0.f;
#pragma unroll
        for (int j = 0; j < 4; j++) {
            b16x8 kv = kr[j];
#pragma unroll
            for (int e = 0; e < 8; e++) s += q[j * 8 + e] * (float)kv[e];
        }
        // closed-form relative-position index: (hi-hj+7)*15 + (wi-wj+7)
        const int ridx = (hi - (n >> 3) + 7) * 15 + (wi - (n & 7) + 7);
        s += rpb_h[ridx] + mrow[n];
        float ee = __expf(s);
        sum += ee;
        const b16x8* vr = (const b16x8*)(kvs + n * 64 + 32);   // broadcast
#pragma unroll
        for (int j = 0; j < 4; j++) {
            b16x8 vv = vr[j];
#pragma unroll
            for (int e = 0; e < 8; e++) o_acc[j * 8 + e] += ee * (float)vv[e];
        }
    }
    const float inv = 1.f / sum;
    __bf16* dst = ctx + (long)(b * NPOS + lane) * DIM + h * HD;
#pragma unroll
    for (int j = 0; j < 4; j++) {
        b16x8 pk;
#pragma unroll
        for (int e = 0; e < 8; e++) pk[e] = (__bf16)(o_acc[j * 8 + e] * inv);
        *(b16x8*)(dst + j * 8) = pk;
    }
}

// ---------------------------------------------------------------------------
extern "C" void kernel_launch(void* const* d_in, const int* in_sizes, int n_in,
                              void* d_out, int out_size, void* d_ws, size_t ws_size,
                              hipStream_t stream)
{
    (void)in_sizes; (void)n_in; (void)out_size; (void)ws_size;
    const float* x      = (const float*)d_in[0];
    const float* mask   = (const float*)d_in[1];
    const float* qkv_w  = (const float*)d_in[2];
    const float* qkv_b  = (const float*)d_in[3];
    const float* dw_w   = (const float*)d_in[4];
    const float* dw_b   = (const float*)d_in[5];
    const float* rpb    = (const float*)d_in[6];
    const float* proj_w = (const float*)d_in[8];
    const float* proj_b = (const float*)d_in[9];
    float* out = (float*)d_out;

    __bf16* t   = (__bf16*)d_ws;                 // (131072, 576) bf16 = 151 MB
    __bf16* ctx = t + (long)MTOT * C3;           // (131072, 192) bf16 =  50 MB

    gemm_bt<float, __bf16><<<(MTOT / GTM) * (C3 / GTN), 256, 0, stream>>>(x, qkv_w, qkv_b, t, C3);
    attn_fused<<<NWIN * HEADS, 64, 0, stream>>>(t, dw_w, dw_b, mask, rpb, ctx);
    gemm_bt<__bf16, float><<<(MTOT / GTM) * (DIM / GTN), 256, 0, stream>>>(ctx, proj_w, proj_b, out, DIM);
}

// Round 4
// 688.428 us; speedup vs baseline: 1.3553x; 1.0323x over previous
//
#include <hip/hip_runtime.h>

#define NWIN 2048
#define NPOS 64
#define DIM  192
#define C3   576
#define HEADS 6
#define HD   32
#define MTOT (NWIN*NPOS)
#define SCALE 0.17677669529663687f

typedef __bf16 b16x8 __attribute__((ext_vector_type(8)));
typedef float  f32x4 __attribute__((ext_vector_type(4)));

// load 8 contiguous elements as bf16x8, converting if fp32
__device__ __forceinline__ b16x8 ld8(const float* p) {
    const f32x4 f0 = *(const f32x4*)p;
    const f32x4 f1 = *(const f32x4*)(p + 4);
    b16x8 r;
    r[0] = (__bf16)f0[0]; r[1] = (__bf16)f0[1]; r[2] = (__bf16)f0[2]; r[3] = (__bf16)f0[3];
    r[4] = (__bf16)f1[0]; r[5] = (__bf16)f1[1]; r[6] = (__bf16)f1[2]; r[7] = (__bf16)f1[3];
    return r;
}
__device__ __forceinline__ b16x8 ld8(const __bf16* p) { return *(const b16x8*)p; }

// ---------------------------------------------------------------------------
// GEMM (B^T form): C[m][n] = sum_k A[m][k] * W[n][k] + bias[n]
// Tile 128(M) x 64(N), BK=64 (3 chunks), 256 threads = 4 waves.
// launch_bounds(256,3): 3 blocks/CU (LDS 27.6 KB x3 = 83 KB <= 160).
// ---------------------------------------------------------------------------
#define GTM 128
#define GTN 64
#define GLD 72

template <typename TA, typename TC>
__global__ __launch_bounds__(256, 3)
void gemm_bt(const TA* __restrict__ A, const float* __restrict__ W,
             const float* __restrict__ bias, TC* __restrict__ C, int N)
{
    __shared__ __bf16 As[GTM][GLD];
    __shared__ __bf16 Ws[GTN][GLD];
    const int ntiles = N / GTN;
    const int bm = blockIdx.x / ntiles;
    const int bn = blockIdx.x % ntiles;
    const long m0 = (long)bm * GTM;
    const int  n0 = bn * GTN;
    const int tid  = threadIdx.x;
    const int wave = tid >> 6, lane = tid & 63;
    const int lr = lane & 15, lq = lane >> 4;

    f32x4 acc[2][4];
#pragma unroll
    for (int i = 0; i < 2; i++)
#pragma unroll
        for (int j = 0; j < 4; j++) acc[i][j] = (f32x4){0.f, 0.f, 0.f, 0.f};

    for (int kc = 0; kc < 3; kc++) {
#pragma unroll
        for (int i = 0; i < 4; i++) {
            int idx = tid + i * 256;
            int r = idx >> 3, c = idx & 7;
            *(b16x8*)&As[r][c * 8] = ld8(A + (m0 + r) * 192 + kc * 64 + c * 8);
        }
#pragma unroll
        for (int i = 0; i < 2; i++) {
            int idx = tid + i * 256;
            int r = idx >> 3, c = idx & 7;
            *(b16x8*)&Ws[r][c * 8] = ld8(W + (long)(n0 + r) * 192 + kc * 64 + c * 8);
        }
        __syncthreads();
#pragma unroll
        for (int kt = 0; kt < 2; kt++) {
            const int k0 = kt * 32 + lq * 8;
            b16x8 a0 = *(const b16x8*)&As[wave * 32 + lr][k0];
            b16x8 a1 = *(const b16x8*)&As[wave * 32 + 16 + lr][k0];
            b16x8 b0 = *(const b16x8*)&Ws[lr][k0];
            b16x8 b1 = *(const b16x8*)&Ws[16 + lr][k0];
            b16x8 b2 = *(const b16x8*)&Ws[32 + lr][k0];
            b16x8 b3 = *(const b16x8*)&Ws[48 + lr][k0];
            acc[0][0] = __builtin_amdgcn_mfma_f32_16x16x32_bf16(a0, b0, acc[0][0], 0, 0, 0);
            acc[0][1] = __builtin_amdgcn_mfma_f32_16x16x32_bf16(a0, b1, acc[0][1], 0, 0, 0);
            acc[0][2] = __builtin_amdgcn_mfma_f32_16x16x32_bf16(a0, b2, acc[0][2], 0, 0, 0);
            acc[0][3] = __builtin_amdgcn_mfma_f32_16x16x32_bf16(a0, b3, acc[0][3], 0, 0, 0);
            acc[1][0] = __builtin_amdgcn_mfma_f32_16x16x32_bf16(a1, b0, acc[1][0], 0, 0, 0);
            acc[1][1] = __builtin_amdgcn_mfma_f32_16x16x32_bf16(a1, b1, acc[1][1], 0, 0, 0);
            acc[1][2] = __builtin_amdgcn_mfma_f32_16x16x32_bf16(a1, b2, acc[1][2], 0, 0, 0);
            acc[1][3] = __builtin_amdgcn_mfma_f32_16x16x32_bf16(a1, b3, acc[1][3], 0, 0, 0);
        }
        __syncthreads();
    }
#pragma unroll
    for (int tn = 0; tn < 4; tn++) {
        float bv = bias[n0 + tn * 16 + lr];
#pragma unroll
        for (int tm = 0; tm < 2; tm++) {
#pragma unroll
            for (int r = 0; r < 4; r++) {
                long row = m0 + wave * 32 + tm * 16 + lq * 4 + r;
                C[row * N + (n0 + tn * 16 + lr)] = (TC)(acc[tm][tn][r] + bv);
            }
        }
    }
}

// ---------------------------------------------------------------------------
// Fused depthwise-conv + MFMA window attention. One wave per (window b, head h).
// grid = NWIN*HEADS, 64 threads. XCD swizzle: consecutive b (all 6 heads) on
// the same XCD so halo rows (b-1,b,b+1) hit L2 instead of HBM.
// LDS (bf16 elems):  [0,2560) Q rows stride 40 | [2560,5120) K rows stride 40
//                    [0,4608) P rows stride 72 (overlays Q,K after QK done)
//                    [5120,7424) V^T rows stride 72 (32 rows of 64 keys)
// QK^T: 16x  mfma_16x16x32 (A=Q frag, B=K[key][d] rows)
// softmax: C-layout bias (closed-form rel idx + mask) + expf, row sums via
//          shfl_xor butterfly over the 16-lane col groups
// PV:   16x mfma (A=P frag, B=V^T rows), normalize by row sum, store ctx.
// ---------------------------------------------------------------------------
#define Q0 0
#define K0 2560
#define P0 0
#define V0 5120

__global__ __launch_bounds__(64, 4)
void attn_fused(const __bf16* __restrict__ t, const float* __restrict__ dw_w,
                const float* __restrict__ dw_b, const float* __restrict__ mask,
                const float* __restrict__ rpb, __bf16* __restrict__ ctx)
{
    __shared__ __bf16 smem[7424];
    __shared__ float  rpb_h[225];
    const int bid = blockIdx.x;
    const int h   = bid >> 11;
    const int s_  = bid & 2047;
    const int b   = (s_ & 7) * 256 + (s_ >> 3);   // blockIdx%8 == b/256 -> XCD-stable
    const int lane = threadIdx.x;
    const int lr = lane & 15, lq = lane >> 4;

    for (int i = lane; i < 225; i += 64) rpb_h[i] = rpb[i * HEADS + h];

    // ---- Phase A: rolling 3x3 depthwise conv for k,v of head h -> LDS ----
    {
        const int kv = lane >> 5, d = lane & 31;
        const int o  = 192 + kv * 192 + h * 32 + d;
        float w[9];
#pragma unroll
        for (int tap = 0; tap < 9; tap++) w[tap] = dw_w[o * 9 + tap];
        const float cb = dw_b[o];
        const bool up = (b > 0), dn = (b < NWIN - 1);
        const __bf16* r1 = t + (long)b * NPOS * C3 + o;
        const __bf16* r0 = r1 - (long)NPOS * C3;
        const __bf16* r2 = r1 + (long)NPOS * C3;
        float p0 = 0.f, c0 = up ? (float)r0[0] : 0.f;
        float p1 = 0.f, c1 = (float)r1[0];
        float p2 = 0.f, c2 = dn ? (float)r2[0] : 0.f;
        const int base = kv ? (V0 + d * 72) : (K0 + d);
        const int step = kv ? 1 : 40;
        for (int nn = 0; nn < 64; nn++) {
            float n0 = 0.f, n1 = 0.f, n2 = 0.f;
            if (nn < 63) {
                const long off = (long)(nn + 1) * C3;
                if (up) n0 = (float)r0[off];
                n1 = (float)r1[off];
                if (dn) n2 = (float)r2[off];
            }
            float out = cb
                + w[0] * p0 + w[1] * c0 + w[2] * n0
                + w[3] * p1 + w[4] * c1 + w[5] * n1
                + w[6] * p2 + w[7] * c2 + w[8] * n2;
            smem[base + nn * step] = (__bf16)out;
            p0 = c0; c0 = n0; p1 = c1; c1 = n1; p2 = c2; c2 = n2;
        }
    }

    // ---- Phase B: q conv per lane (lane = query row) -> Q LDS ----
    {
        float q[HD];
#pragma unroll
        for (int d = 0; d < HD; d++) q[d] = dw_b[h * HD + d];
#pragma unroll
        for (int kh = 0; kh < 3; kh++) {
            const int bb = b + kh - 1;
            if (bb < 0 || bb >= NWIN) continue;   // block-uniform
#pragma unroll
            for (int kw = 0; kw < 3; kw++) {
                const int nn = lane + kw - 1;
                if (nn >= 0 && nn < NPOS) {
                    const b16x8* p = (const b16x8*)(t + (long)(bb * NPOS + nn) * C3 + h * HD);
#pragma unroll
                    for (int j = 0; j < 4; j++) {
                        b16x8 vv = p[j];
#pragma unroll
                        for (int e = 0; e < 8; e++)
                            q[j * 8 + e] += (float)vv[e] * dw_w[(h * HD + j * 8 + e) * 9 + kh * 3 + kw];
                    }
                }
            }
        }
#pragma unroll
        for (int d = 0; d < HD; d++) smem[Q0 + lane * 40 + d] = (__bf16)(q[d] * SCALE);
    }

    __syncthreads();

    // ---- QK^T via MFMA: S[64][64] ----
    b16x8 aq[4], bk[4];
#pragma unroll
    for (int tm = 0; tm < 4; tm++) aq[tm] = *(const b16x8*)&smem[Q0 + (tm * 16 + lr) * 40 + lq * 8];
#pragma unroll
    for (int tn = 0; tn < 4; tn++) bk[tn] = *(const b16x8*)&smem[K0 + (tn * 16 + lr) * 40 + lq * 8];
    f32x4 S[4][4];
#pragma unroll
    for (int tm = 0; tm < 4; tm++)
#pragma unroll
        for (int tn = 0; tn < 4; tn++) {
            S[tm][tn] = (f32x4){0.f, 0.f, 0.f, 0.f};
            S[tm][tn] = __builtin_amdgcn_mfma_f32_16x16x32_bf16(aq[tm], bk[tn], S[tm][tn], 0, 0, 0);
        }

    __syncthreads();   // Q/K frag reads complete before P overwrites them

    // ---- bias + exp (C-layout) + row-sum partials + P -> LDS ----
    const float* mbase = mask + (long)(b & 63) * 4096;
    float part[4][4];
#pragma unroll
    for (int tm = 0; tm < 4; tm++)
#pragma unroll
        for (int r = 0; r < 4; r++) part[tm][r] = 0.f;
#pragma unroll
    for (int tm = 0; tm < 4; tm++) {
#pragma unroll
        for (int r = 0; r < 4; r++) {
            const int row = tm * 16 + lq * 4 + r;
            const int rh = row >> 3, rw = row & 7;
#pragma unroll
            for (int tn = 0; tn < 4; tn++) {
                const int col = tn * 16 + lr;
                const int ridx = (rh - (col >> 3) + 7) * 15 + (rw - (col & 7) + 7);
                float sv = S[tm][tn][r] + rpb_h[ridx] + mbase[row * 64 + col];
                float ee = __expf(sv);
                part[tm][r] += ee;
                smem[P0 + row * 72 + col] = (__bf16)ee;
            }
        }
    }
    // reduce across the 16 lanes of each col group (lq fixed, lr varies)
#pragma unroll
    for (int st = 1; st < 16; st <<= 1)
#pragma unroll
        for (int tm = 0; tm < 4; tm++)
#pragma unroll
            for (int r = 0; r < 4; r++) part[tm][r] += __shfl_xor(part[tm][r], st);
    float inv[4][4];
#pragma unroll
    for (int tm = 0; tm < 4; tm++)
#pragma unroll
        for (int r = 0; r < 4; r++) inv[tm][r] = 1.0f / part[tm][r];

    __syncthreads();

    // ---- PV via MFMA: O[64][32] ----
    f32x4 O[4][2];
#pragma unroll
    for (int tm = 0; tm < 4; tm++)
#pragma unroll
        for (int tn2 = 0; tn2 < 2; tn2++) O[tm][tn2] = (f32x4){0.f, 0.f, 0.f, 0.f};
#pragma unroll
    for (int tk = 0; tk < 2; tk++) {
        b16x8 bv[2];
#pragma unroll
        for (int tn2 = 0; tn2 < 2; tn2++)
            bv[tn2] = *(const b16x8*)&smem[V0 + (tn2 * 16 + lr) * 72 + tk * 32 + lq * 8];
#pragma unroll
        for (int tm = 0; tm < 4; tm++) {
            b16x8 ap = *(const b16x8*)&smem[P0 + (tm * 16 + lr) * 72 + tk * 32 + lq * 8];
#pragma unroll
            for (int tn2 = 0; tn2 < 2; tn2++)
                O[tm][tn2] = __builtin_amdgcn_mfma_f32_16x16x32_bf16(ap, bv[tn2], O[tm][tn2], 0, 0, 0);
        }
    }

    // ---- normalize + store ctx ----
#pragma unroll
    for (int tm = 0; tm < 4; tm++)
#pragma unroll
        for (int tn2 = 0; tn2 < 2; tn2++)
#pragma unroll
            for (int r = 0; r < 4; r++) {
                const int row = tm * 16 + lq * 4 + r;
                ctx[(long)(b * NPOS + row) * DIM + h * HD + tn2 * 16 + lr] =
                    (__bf16)(O[tm][tn2][r] * inv[tm][r]);
            }
}

// ---------------------------------------------------------------------------
extern "C" void kernel_launch(void* const* d_in, const int* in_sizes, int n_in,
                              void* d_out, int out_size, void* d_ws, size_t ws_size,
                              hipStream_t stream)
{
    (void)in_sizes; (void)n_in; (void)out_size; (void)ws_size;
    const float* x      = (const float*)d_in[0];
    const float* mask   = (const float*)d_in[1];
    const float* qkv_w  = (const float*)d_in[2];
    const float* qkv_b  = (const float*)d_in[3];
    const float* dw_w   = (const float*)d_in[4];
    const float* dw_b   = (const float*)d_in[5];
    const float* rpb    = (const float*)d_in[6];
    const float* proj_w = (const float*)d_in[8];
    const float* proj_b = (const float*)d_in[9];
    float* out = (float*)d_out;

    __bf16* t   = (__bf16*)d_ws;                 // (131072, 576) bf16 = 151 MB
    __bf16* ctx = t + (long)MTOT * C3;           // (131072, 192) bf16 =  50 MB

    gemm_bt<float, __bf16><<<(MTOT / GTM) * (C3 / GTN), 256, 0, stream>>>(x, qkv_w, qkv_b, t, C3);
    attn_fused<<<NWIN * HEADS, 64, 0, stream>>>(t, dw_w, dw_b, mask, rpb, ctx);
    gemm_bt<__bf16, float><<<(MTOT / GTM) * (DIM / GTN), 256, 0, stream>>>(ctx, proj_w, proj_b, out, DIM);
}